// Round 1
// baseline (1530.078 us; speedup 1.0000x reference)
//
#include <hip/hip_runtime.h>
#include <stdint.h>
#include <math.h>

// Problem constants (fixed by the reference)
#define B_ 4
#define S_ 1024
#define E_ 1024
#define H_ 16
#define HD_ 64
#define HB_ 64  // H_*B_

// ---------------------------------------------------------------------------
// Bool-dtype detection: attn_mask = triu(ones,k=1) so element [0][1] is True.
// If the harness ships numpy bool (1 byte/elem), byte[1]==1.
// If it normalizes to int32, byte[1] is the 2nd byte of elem 0 (==0).
// ---------------------------------------------------------------------------
__global__ void detect_bool_kernel(const uint8_t* __restrict__ amask, int* __restrict__ flag) {
  if (threadIdx.x == 0 && blockIdx.x == 0) {
    *flag = (amask[1] != 0) ? 1 : 0;
  }
}

__device__ __forceinline__ bool read_bool(const void* p, int idx, int isu8) {
  if (isu8) return ((const uint8_t*)p)[idx] != 0;
  return ((const int*)p)[idx] != 0;
}

// ---------------------------------------------------------------------------
// C[M,1024] = A[M,1024] @ W[1024,1024]^T + bias   (fp32, 128x64 tile, BK=16)
// grid = (N/64, M/128), block = 256
// ---------------------------------------------------------------------------
__global__ __launch_bounds__(256) void gemm_bias_kernel(
    const float* __restrict__ A, const float* __restrict__ W,
    const float* __restrict__ bias, float* __restrict__ C) {
  const int K = 1024, N = 1024;
  const int m0 = blockIdx.y * 128, n0 = blockIdx.x * 64;
  __shared__ float As[16][132];  // [k][m], padded row stride = 132 (16B-multiple)
  __shared__ float Bs[16][68];   // [k][n]
  const int t = threadIdx.x;
  const int tx = t & 15, ty = t >> 4;
  float acc[8][4] = {};
  for (int k0 = 0; k0 < K; k0 += 16) {
    {  // A tile: 128 rows x 16 k, 2 float4 per thread
      const int r = t >> 1;
      const int f = (t & 1) * 2;  // float4 index 0 or 2
      const float* src = A + (size_t)(m0 + r) * K + k0 + f * 4;
      float4 v0 = *(const float4*)(src);
      float4 v1 = *(const float4*)(src + 4);
      As[f * 4 + 0][r] = v0.x; As[f * 4 + 1][r] = v0.y;
      As[f * 4 + 2][r] = v0.z; As[f * 4 + 3][r] = v0.w;
      As[f * 4 + 4][r] = v1.x; As[f * 4 + 5][r] = v1.y;
      As[f * 4 + 6][r] = v1.z; As[f * 4 + 7][r] = v1.w;
    }
    {  // W tile: 64 rows x 16 k, 1 float4 per thread
      const int r = t >> 2;
      const int f = t & 3;
      const float* src = W + (size_t)(n0 + r) * K + k0 + f * 4;
      float4 v = *(const float4*)(src);
      Bs[f * 4 + 0][r] = v.x; Bs[f * 4 + 1][r] = v.y;
      Bs[f * 4 + 2][r] = v.z; Bs[f * 4 + 3][r] = v.w;
    }
    __syncthreads();
#pragma unroll
    for (int kk = 0; kk < 16; ++kk) {
      float4 a0 = *(const float4*)&As[kk][ty * 8];
      float4 a1 = *(const float4*)&As[kk][ty * 8 + 4];
      float4 bb = *(const float4*)&Bs[kk][tx * 4];
      float a_[8] = {a0.x, a0.y, a0.z, a0.w, a1.x, a1.y, a1.z, a1.w};
      float b_[4] = {bb.x, bb.y, bb.z, bb.w};
#pragma unroll
      for (int i = 0; i < 8; ++i)
#pragma unroll
        for (int j = 0; j < 4; ++j)
          acc[i][j] = fmaf(a_[i], b_[j], acc[i][j]);
    }
    __syncthreads();
  }
#pragma unroll
  for (int i = 0; i < 8; ++i) {
    const int m = m0 + ty * 8 + i;
#pragma unroll
    for (int j = 0; j < 4; ++j) {
      const int n = n0 + tx * 4 + j;
      C[(size_t)m * N + n] = acc[i][j] + bias[n];
    }
  }
}

// ---------------------------------------------------------------------------
// In-place RoPE on [B,S,E] with per-(b,s) position index.
// One thread per channel pair. Angle computed in double, reduced mod 2pi.
// ---------------------------------------------------------------------------
__global__ __launch_bounds__(256) void rope_kernel(float* __restrict__ X,
                                                   const int* __restrict__ idxs) {
  const int gid = blockIdx.x * 256 + threadIdx.x;  // [0, B*S*E/2)
  const int i = gid & 511;                         // pair index, E/2 = 512
  const int bs = gid >> 9;                         // b*S + s
  const int pos = idxs[bs];
  const double freq = pow(10000.0, -(double)(2 * i) / 1024.0);
  const double ang = fmod((double)pos * freq, 6.283185307179586476925287);
  const float fa = (float)ang;
  const float c = cosf(fa), sn = sinf(fa);
  float2 v = ((float2*)X)[gid];
  float2 r;
  r.x = v.x * c - v.y * sn;
  r.y = v.x * sn + v.y * c;
  ((float2*)X)[gid] = r;
}

// ---------------------------------------------------------------------------
// Scores: Sc[lhb][q][k] = (Q_hb[q,:] . K_hb[k,:]) / 8 + mask
// hb = h*4 + b (head-major); mask batch index bp = hb >> 4 (reference quirk).
// grid = (S/64, S/64, CH), block = 256
// ---------------------------------------------------------------------------
__global__ __launch_bounds__(256) void scores_kernel(
    const float* __restrict__ Qp, const float* __restrict__ Kp,
    const void* __restrict__ amask, const void* __restrict__ kpm,
    const int* __restrict__ flagp, float* __restrict__ Sc, int hb0) {
  const int lhb = blockIdx.z;
  const int hb = hb0 + lhb;
  const int h = hb >> 2, b = hb & 3, bp = hb >> 4;
  const int q0 = blockIdx.y * 64, k0 = blockIdx.x * 64;
  const int isu8 = *flagp;
  __shared__ float Qs[64][68];
  __shared__ float Ks[64][68];
  const int t = threadIdx.x;
  {  // load 64x64 Q and K sub-blocks (head h's 64 dims)
    const int r = t >> 2;
    const int fb = t & 3;
    const float* qsrc = Qp + ((size_t)b * S_ + (q0 + r)) * E_ + h * HD_;
    const float* ksrc = Kp + ((size_t)b * S_ + (k0 + r)) * E_ + h * HD_;
#pragma unroll
    for (int u = 0; u < 4; ++u) {
      const int f4 = fb + 4 * u;
      *(float4*)&Qs[r][f4 * 4] = *(const float4*)(qsrc + f4 * 4);
      *(float4*)&Ks[r][f4 * 4] = *(const float4*)(ksrc + f4 * 4);
    }
  }
  __syncthreads();
  const int tx = t & 15, ty = t >> 4;
  float acc[4][4] = {};
#pragma unroll
  for (int d0 = 0; d0 < 64; d0 += 4) {
    float4 qv[4], kv[4];
#pragma unroll
    for (int i = 0; i < 4; ++i) qv[i] = *(const float4*)&Qs[ty * 4 + i][d0];
#pragma unroll
    for (int j = 0; j < 4; ++j) kv[j] = *(const float4*)&Ks[tx * 4 + j][d0];
#pragma unroll
    for (int i = 0; i < 4; ++i)
#pragma unroll
      for (int j = 0; j < 4; ++j) {
        acc[i][j] = fmaf(qv[i].x, kv[j].x, acc[i][j]);
        acc[i][j] = fmaf(qv[i].y, kv[j].y, acc[i][j]);
        acc[i][j] = fmaf(qv[i].z, kv[j].z, acc[i][j]);
        acc[i][j] = fmaf(qv[i].w, kv[j].w, acc[i][j]);
      }
  }
#pragma unroll
  for (int i = 0; i < 4; ++i) {
    const int q = q0 + ty * 4 + i;
#pragma unroll
    for (int j = 0; j < 4; ++j) {
      const int k = k0 + tx * 4 + j;
      const bool msk = read_bool(amask, q * S_ + k, isu8) ||
                       read_bool(kpm, bp * S_ + k, isu8);
      const float val = msk ? -INFINITY : acc[i][j] * 0.125f;
      Sc[((size_t)lhb << 20) + (size_t)q * S_ + k] = val;
    }
  }
}

// ---------------------------------------------------------------------------
// Row softmax in place + accumulate head-mean into outW [B,S,S].
// One wave per (b, q) row; loops over this chunk's heads for that b.
// grid = (S/4, B), block = 256 (4 waves)
// ---------------------------------------------------------------------------
__global__ __launch_bounds__(256) void softmax_kernel(
    float* __restrict__ Sc, float* __restrict__ outW, int nheads, int first) {
  const int b = blockIdx.y;
  const int wave = threadIdx.x >> 6;
  const int lane = threadIdx.x & 63;
  const int q = blockIdx.x * 4 + wave;
  float wacc[16];
#pragma unroll
  for (int i = 0; i < 16; ++i) wacc[i] = 0.f;
  for (int hh = 0; hh < nheads; ++hh) {
    const int lhb = hh * 4 + b;  // chunk-local hb with same b
    float* row = Sc + ((size_t)lhb << 20) + (size_t)q * S_;
    float x[16];
#pragma unroll
    for (int j = 0; j < 4; ++j) {
      float4 v = ((float4*)row)[j * 64 + lane];
      x[j * 4 + 0] = v.x; x[j * 4 + 1] = v.y;
      x[j * 4 + 2] = v.z; x[j * 4 + 3] = v.w;
    }
    float m = -INFINITY;
#pragma unroll
    for (int i = 0; i < 16; ++i) m = fmaxf(m, x[i]);
    for (int o = 32; o > 0; o >>= 1) m = fmaxf(m, __shfl_xor(m, o));
    float s = 0.f;
#pragma unroll
    for (int i = 0; i < 16; ++i) { x[i] = expf(x[i] - m); s += x[i]; }
    for (int o = 32; o > 0; o >>= 1) s += __shfl_xor(s, o);
    const float inv = 1.0f / s;
#pragma unroll
    for (int j = 0; j < 4; ++j) {
      float4 v;
      v.x = x[j * 4 + 0] * inv; v.y = x[j * 4 + 1] * inv;
      v.z = x[j * 4 + 2] * inv; v.w = x[j * 4 + 3] * inv;
      ((float4*)row)[j * 64 + lane] = v;
      wacc[j * 4 + 0] += v.x; wacc[j * 4 + 1] += v.y;
      wacc[j * 4 + 2] += v.z; wacc[j * 4 + 3] += v.w;
    }
  }
  float* orow = outW + ((size_t)(b * S_ + q)) * S_;
  const float invH = 1.0f / 16.0f;
#pragma unroll
  for (int j = 0; j < 4; ++j) {
    float4 v;
    v.x = wacc[j * 4 + 0] * invH; v.y = wacc[j * 4 + 1] * invH;
    v.z = wacc[j * 4 + 2] * invH; v.w = wacc[j * 4 + 3] * invH;
    if (!first) {
      float4 old = ((float4*)orow)[j * 64 + lane];
      v.x += old.x; v.y += old.y; v.z += old.z; v.w += old.w;
    }
    ((float4*)orow)[j * 64 + lane] = v;
  }
}

// ---------------------------------------------------------------------------
// PV: Ocat[b][q][h*64+d] = sum_k w[lhb][q][k] * Vp[b][k][h*64+d]
// grid = (S/64, CH), block = 256
// ---------------------------------------------------------------------------
__global__ __launch_bounds__(256) void pv_kernel(
    const float* __restrict__ Sc, const float* __restrict__ Vp,
    float* __restrict__ Ocat, int hb0) {
  const int lhb = blockIdx.y;
  const int hb = hb0 + lhb;
  const int h = hb >> 2, b = hb & 3;
  const int q0 = blockIdx.x * 64;
  __shared__ float Ws[64][68];  // [q][kk]
  __shared__ float Vs[64][68];  // [kk][d]
  const int t = threadIdx.x;
  const int tx = t & 15, ty = t >> 4;
  float acc[4][4] = {};
  for (int kt = 0; kt < 16; ++kt) {
    const int r = t >> 2;
    const int fb = t & 3;
    const float* wsrc = Sc + ((size_t)lhb << 20) + (size_t)(q0 + r) * S_ + kt * 64;
    const float* vsrc = Vp + ((size_t)b * S_ + (kt * 64 + r)) * E_ + h * HD_;
#pragma unroll
    for (int u = 0; u < 4; ++u) {
      const int f4 = fb + 4 * u;
      *(float4*)&Ws[r][f4 * 4] = *(const float4*)(wsrc + f4 * 4);
      *(float4*)&Vs[r][f4 * 4] = *(const float4*)(vsrc + f4 * 4);
    }
    __syncthreads();
#pragma unroll
    for (int kk0 = 0; kk0 < 64; kk0 += 4) {
      float4 wv[4];
#pragma unroll
      for (int i = 0; i < 4; ++i) wv[i] = *(const float4*)&Ws[ty * 4 + i][kk0];
#pragma unroll
      for (int u = 0; u < 4; ++u) {
        const float4 vv = *(const float4*)&Vs[kk0 + u][tx * 4];
        const float b_[4] = {vv.x, vv.y, vv.z, vv.w};
#pragma unroll
        for (int i = 0; i < 4; ++i) {
          const float a = (u == 0) ? wv[i].x : (u == 1) ? wv[i].y
                         : (u == 2) ? wv[i].z : wv[i].w;
#pragma unroll
          for (int j = 0; j < 4; ++j)
            acc[i][j] = fmaf(a, b_[j], acc[i][j]);
        }
      }
    }
    __syncthreads();
  }
#pragma unroll
  for (int i = 0; i < 4; ++i)
#pragma unroll
    for (int j = 0; j < 4; ++j)
      Ocat[((size_t)b * S_ + (q0 + ty * 4 + i)) * E_ + h * HD_ + tx * 4 + j] =
          acc[i][j];
}

// ---------------------------------------------------------------------------
extern "C" void kernel_launch(void* const* d_in, const int* in_sizes, int n_in,
                              void* d_out, int out_size, void* d_ws, size_t ws_size,
                              hipStream_t stream) {
  const float* query = (const float*)d_in[0];
  const float* key   = (const float*)d_in[1];
  const float* value = (const float*)d_in[2];
  const int* qidx = (const int*)d_in[3];
  const int* kidx = (const int*)d_in[4];
  const void* amask = d_in[5];
  const void* kpm   = d_in[6];
  const float* Wq = (const float*)d_in[7];
  const float* bq = (const float*)d_in[8];
  const float* Wk = (const float*)d_in[9];
  const float* bk = (const float*)d_in[10];
  const float* Wv = (const float*)d_in[11];
  const float* bv = (const float*)d_in[12];
  const float* Wo = (const float*)d_in[13];
  const float* bo = (const float*)d_in[14];

  float* outA = (float*)d_out;                          // [B,S,E]
  float* outW = (float*)d_out + (size_t)B_ * S_ * E_;   // [B,S,S]

  // ws layout (floats): Qp | Kp | Vp | Ocat | flag(+pad) | Sc(chunk)
  float* ws = (float*)d_ws;
  float* Qp = ws;
  float* Kp = ws + 4194304;
  float* Vp = ws + 8388608;
  float* Ocat = ws + 12582912;
  int* flagp = (int*)(ws + 16777216);
  float* Sc = ws + 16777216 + 64;  // 256 B after flag, 16B-aligned

  // Pick the largest score-chunk (in head-batches) that fits in ws.
  const size_t baseB = (size_t)(16777216 + 64) * sizeof(float);
  int CH = 64;
  while (CH > 4 && baseB + (size_t)CH * (1u << 20) * sizeof(float) > ws_size)
    CH >>= 1;

  detect_bool_kernel<<<1, 64, 0, stream>>>((const uint8_t*)amask, flagp);

  gemm_bias_kernel<<<dim3(16, 32), 256, 0, stream>>>(query, Wq, bq, Qp);
  gemm_bias_kernel<<<dim3(16, 32), 256, 0, stream>>>(key,   Wk, bk, Kp);
  gemm_bias_kernel<<<dim3(16, 32), 256, 0, stream>>>(value, Wv, bv, Vp);

  rope_kernel<<<8192, 256, 0, stream>>>(Qp, qidx);
  rope_kernel<<<8192, 256, 0, stream>>>(Kp, kidx);

  for (int c = 0; c * CH < HB_; ++c) {
    const int hb0 = c * CH;
    scores_kernel<<<dim3(16, 16, CH), 256, 0, stream>>>(Qp, Kp, amask, kpm,
                                                        flagp, Sc, hb0);
    softmax_kernel<<<dim3(256, 4), 256, 0, stream>>>(Sc, outW, CH / 4,
                                                     (c == 0) ? 1 : 0);
    pv_kernel<<<dim3(16, CH), 256, 0, stream>>>(Sc, Vp, Ocat, hb0);
  }

  gemm_bias_kernel<<<dim3(16, 32), 256, 0, stream>>>(Ocat, Wo, bo, outA);
}

// Round 2
// 320.402 us; speedup vs baseline: 4.7755x; 4.7755x over previous
//
#include <hip/hip_runtime.h>
#include <stdint.h>
#include <math.h>

#define B_ 4
#define S_ 1024
#define E_ 1024
#define H_ 16
#define HD_ 64
#define HB_ 64  // H_*B_

typedef __attribute__((ext_vector_type(8))) short bhalf8;
typedef __attribute__((ext_vector_type(4))) float floatx4;

__device__ __forceinline__ unsigned short f2bf(float f) {
  union { float f; unsigned u; } v; v.f = f;
  unsigned r = (v.u + 0x7FFFu + ((v.u >> 16) & 1u)) >> 16;
  return (unsigned short)r;
}
__device__ __forceinline__ float bf2f(unsigned short b) {
  union { unsigned u; float f; } v; v.u = ((unsigned)b) << 16;
  return v.f;
}

__device__ __forceinline__ void gload16(const void* g, void* l) {
  __builtin_amdgcn_global_load_lds(
      (const __attribute__((address_space(1))) unsigned int*)g,
      (__attribute__((address_space(3))) unsigned int*)l, 16, 0, 0);
}

// Stage NCH*8 rows x 64 bf16 (128B rows, global row stride 1024 elems) into
// LDS, linear dest + inverse-swizzled source (involution: byte ^= (row&7)<<4).
template <int NCH>
__device__ __forceinline__ void stage_tile(const unsigned short* org,
                                           unsigned short* lds, int wave, int lane) {
  const int rl = lane >> 3;                      // row within 8-row chunk
  const int scb = ((lane & 7) << 4) ^ (rl << 4); // pre-swizzled source col byte
  const char* base = (const char*)org + scb;
#pragma unroll
  for (int i = 0; i < NCH / 4; ++i) {
    const int c = wave + 4 * i;
    gload16(base + (size_t)(c * 8 + rl) * 2048, (char*)lds + c * 1024);
  }
}

// Read one MFMA operand fragment (8 contiguous bf16) with the matching swizzle.
__device__ __forceinline__ bhalf8 read_frag(const unsigned short* lds, int row, int kbyte) {
  const int off = row * 128 + (kbyte ^ ((row & 7) << 4));
  return *(const bhalf8*)((const char*)lds + off);
}

// ---------------------------------------------------------------------------
__global__ void detect_bool_kernel(const uint8_t* __restrict__ amask, int* __restrict__ flag) {
  if (threadIdx.x == 0 && blockIdx.x == 0) *flag = (amask[1] != 0) ? 1 : 0;
}

// fp32 -> bf16 for the 3 activation inputs (z selects tensor)
__global__ __launch_bounds__(256) void cvt_in_kernel(
    const float* __restrict__ q, const float* __restrict__ k,
    const float* __restrict__ v, unsigned short* __restrict__ Ab) {
  const int z = blockIdx.z;
  const float* src = (z == 0) ? q : (z == 1) ? k : v;
  unsigned short* dst = Ab + (size_t)z * 4194304;
  const size_t i = ((size_t)blockIdx.x * 256 + threadIdx.x) * 8;
  float4 a = *(const float4*)(src + i);
  float4 b = *(const float4*)(src + i + 4);
  bhalf8 r;
  r[0] = (short)f2bf(a.x); r[1] = (short)f2bf(a.y);
  r[2] = (short)f2bf(a.z); r[3] = (short)f2bf(a.w);
  r[4] = (short)f2bf(b.x); r[5] = (short)f2bf(b.y);
  r[6] = (short)f2bf(b.z); r[7] = (short)f2bf(b.w);
  *(bhalf8*)(dst + i) = r;
}

// fp32 -> bf16 for the 4 weight matrices
__global__ __launch_bounds__(256) void cvt_w_kernel(
    const float* __restrict__ wq, const float* __restrict__ wk,
    const float* __restrict__ wv, const float* __restrict__ wo,
    unsigned short* __restrict__ Wb) {
  const int z = blockIdx.z;
  const float* src = (z == 0) ? wq : (z == 1) ? wk : (z == 2) ? wv : wo;
  unsigned short* dst = Wb + (size_t)z * 1048576;
  const size_t i = ((size_t)blockIdx.x * 256 + threadIdx.x) * 8;
  float4 a = *(const float4*)(src + i);
  float4 b = *(const float4*)(src + i + 4);
  bhalf8 r;
  r[0] = (short)f2bf(a.x); r[1] = (short)f2bf(a.y);
  r[2] = (short)f2bf(a.z); r[3] = (short)f2bf(a.w);
  r[4] = (short)f2bf(b.x); r[5] = (short)f2bf(b.y);
  r[6] = (short)f2bf(b.z); r[7] = (short)f2bf(b.w);
  *(bhalf8*)(dst + i) = r;
}

// ---------------------------------------------------------------------------
// C[4096,1024] = A @ W^T + bias. 128x128 tile, BK=64, 4 waves (2x2 quadrants).
// z selects one of up to 3 (A, W, bias, C) sets.
// ---------------------------------------------------------------------------
template <bool BF16OUT>
__global__ __launch_bounds__(256) void mfma_gemm_kernel(
    const unsigned short* __restrict__ A0, const unsigned short* __restrict__ A1,
    const unsigned short* __restrict__ A2,
    const unsigned short* __restrict__ W0, const unsigned short* __restrict__ W1,
    const unsigned short* __restrict__ W2,
    const float* __restrict__ b0, const float* __restrict__ b1,
    const float* __restrict__ b2,
    void* __restrict__ C0, void* __restrict__ C1, void* __restrict__ C2) {
  const int z = blockIdx.z;
  const unsigned short* A = (z == 0) ? A0 : (z == 1) ? A1 : A2;
  const unsigned short* W = (z == 0) ? W0 : (z == 1) ? W1 : W2;
  const float* bias = (z == 0) ? b0 : (z == 1) ? b1 : b2;
  void* C = (z == 0) ? C0 : (z == 1) ? C1 : C2;
  const int m0 = blockIdx.y * 128, n0 = blockIdx.x * 128;
  __shared__ unsigned short As[128 * 64];
  __shared__ unsigned short Ws[128 * 64];
  const int t = threadIdx.x, wave = t >> 6, lane = t & 63;
  const int wr = wave >> 1, wc = wave & 1;
  floatx4 acc[4][4];
  const floatx4 z4 = {0.f, 0.f, 0.f, 0.f};
#pragma unroll
  for (int i = 0; i < 4; ++i)
#pragma unroll
    for (int j = 0; j < 4; ++j) acc[i][j] = z4;

  for (int k0 = 0; k0 < 1024; k0 += 64) {
    stage_tile<16>(A + (size_t)m0 * 1024 + k0, As, wave, lane);
    stage_tile<16>(W + (size_t)n0 * 1024 + k0, Ws, wave, lane);
    __syncthreads();
#pragma unroll
    for (int ks = 0; ks < 2; ++ks) {
      const int kb = ks * 64 + ((lane >> 4) << 4);
      bhalf8 af[4], bf[4];
#pragma unroll
      for (int mi = 0; mi < 4; ++mi)
        af[mi] = read_frag(As, wr * 64 + mi * 16 + (lane & 15), kb);
#pragma unroll
      for (int ni = 0; ni < 4; ++ni)
        bf[ni] = read_frag(Ws, wc * 64 + ni * 16 + (lane & 15), kb);
#pragma unroll
      for (int mi = 0; mi < 4; ++mi)
#pragma unroll
        for (int ni = 0; ni < 4; ++ni)
          acc[mi][ni] = __builtin_amdgcn_mfma_f32_16x16x32_bf16(af[mi], bf[ni], acc[mi][ni], 0, 0, 0);
    }
    __syncthreads();
  }
#pragma unroll
  for (int mi = 0; mi < 4; ++mi)
#pragma unroll
    for (int ni = 0; ni < 4; ++ni) {
      const int col = n0 + wc * 64 + ni * 16 + (lane & 15);
      const float bv = bias[col];
#pragma unroll
      for (int r = 0; r < 4; ++r) {
        const int row = m0 + wr * 64 + mi * 16 + (lane >> 4) * 4 + r;
        const float v = acc[mi][ni][r] + bv;
        if (BF16OUT)
          ((unsigned short*)C)[(size_t)row * 1024 + col] = f2bf(v);
        else
          ((float*)C)[(size_t)row * 1024 + col] = v;
      }
    }
}

// ---------------------------------------------------------------------------
// In-place RoPE on bf16 [B,S,E]; one thread per channel pair.
// ---------------------------------------------------------------------------
__global__ __launch_bounds__(256) void rope_bf_kernel(unsigned int* __restrict__ X,
                                                      const int* __restrict__ idxs) {
  const int gid = blockIdx.x * 256 + threadIdx.x;  // [0, B*S*E/2)
  const int i = gid & 511, bs = gid >> 9;
  const int pos = idxs[bs];
  const double freq = exp(-(double)(2 * i) * (9.210340371976184 / 1024.0));
  const double ang = fmod((double)pos * freq, 6.283185307179586476925287);
  const float fa = (float)ang;
  float sn, c;
  sincosf(fa, &sn, &c);
  const unsigned v = X[gid];
  const float x = bf2f((unsigned short)(v & 0xffffu));
  const float y = bf2f((unsigned short)(v >> 16));
  const float rx = x * c - y * sn;
  const float ry = x * sn + y * c;
  X[gid] = (unsigned)f2bf(rx) | ((unsigned)f2bf(ry) << 16);
}

// ---------------------------------------------------------------------------
// Vt[(b*16+h)*64 + d][s] = Vr[b][s][h*64+d]   (bf16 transpose, 64x64 tiles)
// grid (16 s-tiles, 64 bh)
// ---------------------------------------------------------------------------
__global__ __launch_bounds__(256) void transpose_v_kernel(
    const unsigned short* __restrict__ Vr, unsigned short* __restrict__ Vt) {
  const int s0 = blockIdx.x * 64;
  const int bh = blockIdx.y;
  const int b = bh >> 4, h = bh & 15;
  __shared__ unsigned short L[64][72];
  const int t = threadIdx.x, r = t >> 2, cq = (t & 3) * 16;
  const unsigned short* src = Vr + ((size_t)(b * S_) + s0 + r) * E_ + h * HD_ + cq;
  *(bhalf8*)&L[r][cq] = *(const bhalf8*)src;
  *(bhalf8*)&L[r][cq + 8] = *(const bhalf8*)(src + 8);
  __syncthreads();
  bhalf8 o0, o1;
#pragma unroll
  for (int u = 0; u < 8; ++u) o0[u] = (short)L[cq + u][r];
#pragma unroll
  for (int u = 0; u < 8; ++u) o1[u] = (short)L[cq + 8 + u][r];
  unsigned short* dst = Vt + ((size_t)bh * 64 + r) * 1024 + s0 + cq;
  *(bhalf8*)dst = o0;
  *(bhalf8*)(dst + 8) = o1;
}

// ---------------------------------------------------------------------------
// Scores (no mask): Sc[lhb][q][k] = 0.125 * Q_hb[q,:].K_hb[k,:]
// grid (8 k-tiles, 8 q-tiles, CH); 128x128 tile, K=64 single step.
// ---------------------------------------------------------------------------
__global__ __launch_bounds__(256) void scores_mfma_kernel(
    const unsigned short* __restrict__ Qb, const unsigned short* __restrict__ Kb,
    float* __restrict__ Sc, int hb0) {
  const int lhb = blockIdx.z, hb = hb0 + lhb;
  const int h = hb >> 2, b = hb & 3;
  const int q0 = blockIdx.y * 128, k0 = blockIdx.x * 128;
  __shared__ unsigned short Qs[128 * 64];
  __shared__ unsigned short Ks[128 * 64];
  const int t = threadIdx.x, wave = t >> 6, lane = t & 63;
  const int wr = wave >> 1, wc = wave & 1;
  floatx4 acc[4][4];
  const floatx4 z4 = {0.f, 0.f, 0.f, 0.f};
#pragma unroll
  for (int i = 0; i < 4; ++i)
#pragma unroll
    for (int j = 0; j < 4; ++j) acc[i][j] = z4;

  stage_tile<16>(Qb + ((size_t)(b * S_) + q0) * E_ + h * HD_, Qs, wave, lane);
  stage_tile<16>(Kb + ((size_t)(b * S_) + k0) * E_ + h * HD_, Ks, wave, lane);
  __syncthreads();
#pragma unroll
  for (int ks = 0; ks < 2; ++ks) {
    const int kb = ks * 64 + ((lane >> 4) << 4);
    bhalf8 af[4], bf[4];
#pragma unroll
    for (int mi = 0; mi < 4; ++mi)
      af[mi] = read_frag(Qs, wr * 64 + mi * 16 + (lane & 15), kb);
#pragma unroll
    for (int ni = 0; ni < 4; ++ni)
      bf[ni] = read_frag(Ks, wc * 64 + ni * 16 + (lane & 15), kb);
#pragma unroll
    for (int mi = 0; mi < 4; ++mi)
#pragma unroll
      for (int ni = 0; ni < 4; ++ni)
        acc[mi][ni] = __builtin_amdgcn_mfma_f32_16x16x32_bf16(af[mi], bf[ni], acc[mi][ni], 0, 0, 0);
  }
  float* out = Sc + ((size_t)lhb << 20);
#pragma unroll
  for (int mi = 0; mi < 4; ++mi)
#pragma unroll
    for (int ni = 0; ni < 4; ++ni) {
      const int k = k0 + wc * 64 + ni * 16 + (lane & 15);
#pragma unroll
      for (int r = 0; r < 4; ++r) {
        const int q = q0 + wr * 64 + mi * 16 + (lane >> 4) * 4 + r;
        out[(size_t)q * 1024 + k] = acc[mi][ni][r] * 0.125f;
      }
    }
}

// ---------------------------------------------------------------------------
// Mask + row softmax + bf16 weights + head-mean accumulation.
// One wave per (b,q) row; loops over this chunk's heads for that b.
// ---------------------------------------------------------------------------
__global__ __launch_bounds__(256) void softmax_kernel(
    const float* __restrict__ Sc, unsigned short* __restrict__ Wt,
    float* __restrict__ outW, const void* __restrict__ amask,
    const void* __restrict__ kpm, const int* __restrict__ flagp,
    int nheads, int hb0, int first) {
  const int b = blockIdx.y;
  const int wave = threadIdx.x >> 6, lane = threadIdx.x & 63;
  const int q = blockIdx.x * 4 + wave;
  const int isu8 = *flagp;

  bool am[16];
  if (isu8) {
    const uchar4* ap = (const uchar4*)((const uint8_t*)amask + (size_t)q * 1024);
#pragma unroll
    for (int j = 0; j < 4; ++j) {
      uchar4 v = ap[j * 64 + lane];
      am[j * 4 + 0] = v.x != 0; am[j * 4 + 1] = v.y != 0;
      am[j * 4 + 2] = v.z != 0; am[j * 4 + 3] = v.w != 0;
    }
  } else {
    const int4* ap = (const int4*)((const int*)amask + (size_t)q * 1024);
#pragma unroll
    for (int j = 0; j < 4; ++j) {
      int4 v = ap[j * 64 + lane];
      am[j * 4 + 0] = v.x != 0; am[j * 4 + 1] = v.y != 0;
      am[j * 4 + 2] = v.z != 0; am[j * 4 + 3] = v.w != 0;
    }
  }

  float wacc[16];
#pragma unroll
  for (int i = 0; i < 16; ++i) wacc[i] = 0.f;

  for (int hh = 0; hh < nheads; ++hh) {
    const int lhb = hh * 4 + b;
    const int bp = (hb0 + hh * 4 + b) >> 4;
    bool km[16];
    if (isu8) {
      const uchar4* kp = (const uchar4*)((const uint8_t*)kpm + (size_t)bp * 1024);
#pragma unroll
      for (int j = 0; j < 4; ++j) {
        uchar4 v = kp[j * 64 + lane];
        km[j * 4 + 0] = v.x != 0; km[j * 4 + 1] = v.y != 0;
        km[j * 4 + 2] = v.z != 0; km[j * 4 + 3] = v.w != 0;
      }
    } else {
      const int4* kp = (const int4*)((const int*)kpm + (size_t)bp * 1024);
#pragma unroll
      for (int j = 0; j < 4; ++j) {
        int4 v = kp[j * 64 + lane];
        km[j * 4 + 0] = v.x != 0; km[j * 4 + 1] = v.y != 0;
        km[j * 4 + 2] = v.z != 0; km[j * 4 + 3] = v.w != 0;
      }
    }
    const float* row = Sc + ((size_t)lhb << 20) + (size_t)q * 1024;
    float x[16];
#pragma unroll
    for (int j = 0; j < 4; ++j) {
      float4 v = ((const float4*)row)[j * 64 + lane];
      x[j * 4 + 0] = v.x; x[j * 4 + 1] = v.y;
      x[j * 4 + 2] = v.z; x[j * 4 + 3] = v.w;
    }
#pragma unroll
    for (int i = 0; i < 16; ++i)
      if (am[i] || km[i]) x[i] = -INFINITY;
    float m = -INFINITY;
#pragma unroll
    for (int i = 0; i < 16; ++i) m = fmaxf(m, x[i]);
    for (int o = 32; o > 0; o >>= 1) m = fmaxf(m, __shfl_xor(m, o));
    float s = 0.f;
#pragma unroll
    for (int i = 0; i < 16; ++i) { x[i] = expf(x[i] - m); s += x[i]; }
    for (int o = 32; o > 0; o >>= 1) s += __shfl_xor(s, o);
    const float inv = 1.0f / s;
    unsigned short* wrow = Wt + ((size_t)lhb << 20) + (size_t)q * 1024;
#pragma unroll
    for (int j = 0; j < 4; ++j) {
      float v0 = x[j * 4 + 0] * inv, v1 = x[j * 4 + 1] * inv;
      float v2 = x[j * 4 + 2] * inv, v3 = x[j * 4 + 3] * inv;
      ushort4 w4;
      w4.x = f2bf(v0); w4.y = f2bf(v1); w4.z = f2bf(v2); w4.w = f2bf(v3);
      ((ushort4*)wrow)[j * 64 + lane] = w4;
      wacc[j * 4 + 0] += v0; wacc[j * 4 + 1] += v1;
      wacc[j * 4 + 2] += v2; wacc[j * 4 + 3] += v3;
    }
  }
  float* orow = outW + ((size_t)(b * S_ + q)) * S_;
  const float invH = 1.0f / 16.0f;
#pragma unroll
  for (int j = 0; j < 4; ++j) {
    float4 v;
    v.x = wacc[j * 4 + 0] * invH; v.y = wacc[j * 4 + 1] * invH;
    v.z = wacc[j * 4 + 2] * invH; v.w = wacc[j * 4 + 3] * invH;
    if (!first) {
      float4 old = ((float4*)orow)[j * 64 + lane];
      v.x += old.x; v.y += old.y; v.z += old.z; v.w += old.w;
    }
    ((float4*)orow)[j * 64 + lane] = v;
  }
}

// ---------------------------------------------------------------------------
// PV: Ocat[b][q][h*64+d] = sum_k Wt[lhb][q][k] * Vt[bh*64+d][k]
// grid (8 q-tiles, CH); 128 q x 64 d per block, BK=64, wave owns 32x64.
// ---------------------------------------------------------------------------
__global__ __launch_bounds__(256) void pv_mfma_kernel(
    const unsigned short* __restrict__ Wt, const unsigned short* __restrict__ Vt,
    unsigned short* __restrict__ Ocat, int hb0) {
  const int lhb = blockIdx.y, hb = hb0 + lhb;
  const int h = hb >> 2, b = hb & 3;
  const int q0 = blockIdx.x * 128;
  __shared__ unsigned short Ps[128 * 64];
  __shared__ unsigned short Vs[64 * 64];
  const int t = threadIdx.x, wave = t >> 6, lane = t & 63;
  const unsigned short* Wh = Wt + ((size_t)lhb << 20);
  const unsigned short* Vh = Vt + (size_t)(b * 16 + h) * 64 * 1024;
  floatx4 acc[2][4];
  const floatx4 z4 = {0.f, 0.f, 0.f, 0.f};
#pragma unroll
  for (int i = 0; i < 2; ++i)
#pragma unroll
    for (int j = 0; j < 4; ++j) acc[i][j] = z4;

  for (int k0 = 0; k0 < 1024; k0 += 64) {
    stage_tile<16>(Wh + (size_t)q0 * 1024 + k0, Ps, wave, lane);
    stage_tile<8>(Vh + k0, Vs, wave, lane);
    __syncthreads();
#pragma unroll
    for (int ks = 0; ks < 2; ++ks) {
      const int kb = ks * 64 + ((lane >> 4) << 4);
      bhalf8 af[2], bf[4];
#pragma unroll
      for (int mi = 0; mi < 2; ++mi)
        af[mi] = read_frag(Ps, wave * 32 + mi * 16 + (lane & 15), kb);
#pragma unroll
      for (int ni = 0; ni < 4; ++ni)
        bf[ni] = read_frag(Vs, ni * 16 + (lane & 15), kb);
#pragma unroll
      for (int mi = 0; mi < 2; ++mi)
#pragma unroll
        for (int ni = 0; ni < 4; ++ni)
          acc[mi][ni] = __builtin_amdgcn_mfma_f32_16x16x32_bf16(af[mi], bf[ni], acc[mi][ni], 0, 0, 0);
    }
    __syncthreads();
  }
#pragma unroll
  for (int mi = 0; mi < 2; ++mi)
#pragma unroll
    for (int ni = 0; ni < 4; ++ni) {
      const int d = ni * 16 + (lane & 15);
#pragma unroll
      for (int r = 0; r < 4; ++r) {
        const int q = q0 + wave * 32 + mi * 16 + (lane >> 4) * 4 + r;
        Ocat[((size_t)(b * S_) + q) * E_ + h * HD_ + d] = f2bf(acc[mi][ni][r]);
      }
    }
}

// ---------------------------------------------------------------------------
extern "C" void kernel_launch(void* const* d_in, const int* in_sizes, int n_in,
                              void* d_out, int out_size, void* d_ws, size_t ws_size,
                              hipStream_t stream) {
  (void)in_sizes; (void)n_in; (void)out_size;
  const float* query = (const float*)d_in[0];
  const float* key   = (const float*)d_in[1];
  const float* value = (const float*)d_in[2];
  const int* qidx = (const int*)d_in[3];
  const int* kidx = (const int*)d_in[4];
  const void* amask = d_in[5];
  const void* kpm   = d_in[6];
  const float* Wq = (const float*)d_in[7];
  const float* bq = (const float*)d_in[8];
  const float* Wk = (const float*)d_in[9];
  const float* bk = (const float*)d_in[10];
  const float* Wv = (const float*)d_in[11];
  const float* bv = (const float*)d_in[12];
  const float* Wo = (const float*)d_in[13];
  const float* bo = (const float*)d_in[14];

  float* outA = (float*)d_out;                          // [B,S,E] fp32
  float* outW = (float*)d_out + (size_t)B_ * S_ * E_;   // [B,S,S] fp32

  float* ws = (float*)d_ws;
  // Layout (float offsets):
  unsigned short* Ab   = (unsigned short*)(ws + 0);         // 3x 4,194,304 bf16 (6,291,456 fl)
  unsigned short* Wb   = (unsigned short*)(ws + 6291456);   // 4x 1,048,576 bf16 (2,097,152 fl)
  unsigned short* Qr   = (unsigned short*)(ws + 8388608);   // 4,194,304 bf16
  unsigned short* Kr   = (unsigned short*)(ws + 10485760);
  unsigned short* Vr   = (unsigned short*)(ws + 12582912);
  unsigned short* Vt   = (unsigned short*)(ws + 14680064);
  unsigned short* Ocat = (unsigned short*)(ws + 16777216);
  int* flagp           = (int*)(ws + 18874368);
  const size_t tail_off = 18874432;  // floats; base = 75.5 MB

  // Chunk sizing: per head-batch needs 1,048,576 (Sc fp32) + 524,288 (Wt bf16) floats.
  const size_t ws_floats = ws_size / 4;
  int CH = 0;
  float* Sc = nullptr;
  unsigned short* Wtp = nullptr;
  for (int c = 64; c >= 4; c >>= 1) {
    const size_t need = (size_t)c * (1048576 + 524288);
    if (tail_off + need <= ws_floats) {
      CH = c;
      Sc = ws + tail_off;
      Wtp = (unsigned short*)(ws + tail_off + (size_t)c * 1048576);
      break;
    }
  }
  if (!CH) {  // alias the dead Ab region (6,291,456 floats >= 4*1.5M)
    CH = 4;
    Sc = ws;
    Wtp = (unsigned short*)(ws + 4194304);
  }

  detect_bool_kernel<<<1, 64, 0, stream>>>((const uint8_t*)amask, flagp);

  cvt_in_kernel<<<dim3(2048, 1, 3), 256, 0, stream>>>(query, key, value, Ab);
  cvt_w_kernel<<<dim3(512, 1, 4), 256, 0, stream>>>(Wq, Wk, Wv, Wo, Wb);

  // Fused QKV projections (bf16 out)
  mfma_gemm_kernel<true><<<dim3(8, 32, 3), 256, 0, stream>>>(
      Ab, Ab + 4194304, Ab + 8388608,
      Wb, Wb + 1048576, Wb + 2097152,
      bq, bk, bv, Qr, Kr, Vr);

  rope_bf_kernel<<<8192, 256, 0, stream>>>((unsigned int*)Qr, qidx);
  rope_bf_kernel<<<8192, 256, 0, stream>>>((unsigned int*)Kr, kidx);

  transpose_v_kernel<<<dim3(16, 64), 256, 0, stream>>>(Vr, Vt);

  const int nch = HB_ / CH;
  for (int c = 0; c < nch; ++c) {
    const int hb0 = c * CH;
    scores_mfma_kernel<<<dim3(8, 8, CH), 256, 0, stream>>>(Qr, Kr, Sc, hb0);
    softmax_kernel<<<dim3(256, 4), 256, 0, stream>>>(Sc, Wtp, outW, amask, kpm,
                                                     flagp, CH / 4, hb0, (c == 0) ? 1 : 0);
    pv_mfma_kernel<<<dim3(8, CH), 256, 0, stream>>>(Wtp, Vt, Ocat, hb0);
  }

  // Output projection (fp32 out)
  mfma_gemm_kernel<false><<<dim3(8, 32, 1), 256, 0, stream>>>(
      Ocat, Ocat, Ocat, Wb + 3145728, Wb + 3145728, Wb + 3145728,
      bo, bo, bo, outA, outA, outA);
}

// Round 3
// 271.320 us; speedup vs baseline: 5.6394x; 1.1809x over previous
//
#include <hip/hip_runtime.h>
#include <stdint.h>
#include <math.h>

#define B_ 4
#define S_ 1024
#define E_ 1024
#define H_ 16
#define HD_ 64
#define HB_ 64  // H_*B_

typedef __attribute__((ext_vector_type(8))) short bhalf8;
typedef __attribute__((ext_vector_type(4))) float floatx4;

__device__ __forceinline__ unsigned short f2bf(float f) {
  union { float f; unsigned u; } v; v.f = f;
  unsigned r = (v.u + 0x7FFFu + ((v.u >> 16) & 1u)) >> 16;
  return (unsigned short)r;
}
__device__ __forceinline__ float bf2f(unsigned short b) {
  union { unsigned u; float f; } v; v.u = ((unsigned)b) << 16;
  return v.f;
}
__device__ __forceinline__ unsigned short f2h(float f) {
  union { _Float16 h; unsigned short u; } v; v.h = (_Float16)f; return v.u;
}
__device__ __forceinline__ float h2f(unsigned short u) {
  union { unsigned short u; _Float16 h; } v; v.u = u; return (float)v.h;
}

__device__ __forceinline__ void gload16(const void* g, void* l) {
  __builtin_amdgcn_global_load_lds(
      (const __attribute__((address_space(1))) unsigned int*)g,
      (__attribute__((address_space(3))) unsigned int*)l, 16, 0, 0);
}

// Stage NCH*8 rows x 64 bf16 (128B rows, global row stride 1024 elems) into
// LDS, linear dest + inverse-swizzled source (involution: byte ^= (row&7)<<4).
template <int NCH>
__device__ __forceinline__ void stage_tile(const unsigned short* org,
                                           unsigned short* lds, int wave, int lane) {
  const int rl = lane >> 3;                      // row within 8-row chunk
  const int scb = ((lane & 7) << 4) ^ (rl << 4); // pre-swizzled source col byte
  const char* base = (const char*)org + scb;
#pragma unroll
  for (int i = 0; i < NCH / 4; ++i) {
    const int c = wave + 4 * i;
    gload16(base + (size_t)(c * 8 + rl) * 2048, (char*)lds + c * 1024);
  }
}

// Read one MFMA operand fragment (8 contiguous bf16) with the matching swizzle.
__device__ __forceinline__ bhalf8 read_frag(const unsigned short* lds, int row, int kbyte) {
  const int off = row * 128 + (kbyte ^ ((row & 7) << 4));
  return *(const bhalf8*)((const char*)lds + off);
}

// ---------------------------------------------------------------------------
__global__ void detect_bool_kernel(const uint8_t* __restrict__ amask, int* __restrict__ flag) {
  if (threadIdx.x == 0 && blockIdx.x == 0) *flag = (amask[1] != 0) ? 1 : 0;
}

// fp32 -> bf16 for the 3 activation inputs (z selects tensor)
__global__ __launch_bounds__(256) void cvt_in_kernel(
    const float* __restrict__ q, const float* __restrict__ k,
    const float* __restrict__ v, unsigned short* __restrict__ Ab) {
  const int z = blockIdx.z;
  const float* src = (z == 0) ? q : (z == 1) ? k : v;
  unsigned short* dst = Ab + (size_t)z * 4194304;
  const size_t i = ((size_t)blockIdx.x * 256 + threadIdx.x) * 8;
  float4 a = *(const float4*)(src + i);
  float4 b = *(const float4*)(src + i + 4);
  bhalf8 r;
  r[0] = (short)f2bf(a.x); r[1] = (short)f2bf(a.y);
  r[2] = (short)f2bf(a.z); r[3] = (short)f2bf(a.w);
  r[4] = (short)f2bf(b.x); r[5] = (short)f2bf(b.y);
  r[6] = (short)f2bf(b.z); r[7] = (short)f2bf(b.w);
  *(bhalf8*)(dst + i) = r;
}

// fp32 -> bf16 for the 4 weight matrices
__global__ __launch_bounds__(256) void cvt_w_kernel(
    const float* __restrict__ wq, const float* __restrict__ wk,
    const float* __restrict__ wv, const float* __restrict__ wo,
    unsigned short* __restrict__ Wb) {
  const int z = blockIdx.z;
  const float* src = (z == 0) ? wq : (z == 1) ? wk : (z == 2) ? wv : wo;
  unsigned short* dst = Wb + (size_t)z * 1048576;
  const size_t i = ((size_t)blockIdx.x * 256 + threadIdx.x) * 8;
  float4 a = *(const float4*)(src + i);
  float4 b = *(const float4*)(src + i + 4);
  bhalf8 r;
  r[0] = (short)f2bf(a.x); r[1] = (short)f2bf(a.y);
  r[2] = (short)f2bf(a.z); r[3] = (short)f2bf(a.w);
  r[4] = (short)f2bf(b.x); r[5] = (short)f2bf(b.y);
  r[6] = (short)f2bf(b.z); r[7] = (short)f2bf(b.w);
  *(bhalf8*)(dst + i) = r;
}

// ---------------------------------------------------------------------------
// C[4096,1024] = A @ W^T + bias. 128x128 tile, BK=64, 4 waves (2x2 quadrants).
// XCD-chunked swizzle on the 256-block (x,y) grid for L2 locality.
// ---------------------------------------------------------------------------
template <bool BF16OUT>
__global__ __launch_bounds__(256) void mfma_gemm_kernel(
    const unsigned short* __restrict__ A0, const unsigned short* __restrict__ A1,
    const unsigned short* __restrict__ A2,
    const unsigned short* __restrict__ W0, const unsigned short* __restrict__ W1,
    const unsigned short* __restrict__ W2,
    const float* __restrict__ b0, const float* __restrict__ b1,
    const float* __restrict__ b2,
    void* __restrict__ C0, void* __restrict__ C1, void* __restrict__ C2) {
  const int z = blockIdx.z;
  const unsigned short* A = (z == 0) ? A0 : (z == 1) ? A1 : A2;
  const unsigned short* W = (z == 0) ? W0 : (z == 1) ? W1 : W2;
  const float* bias = (z == 0) ? b0 : (z == 1) ? b1 : b2;
  void* C = (z == 0) ? C0 : (z == 1) ? C1 : C2;
  // XCD swizzle: 256 blocks -> XCD x gets 32 consecutive tiles (4 m-panels x all n)
  const int lin = blockIdx.y * 8 + blockIdx.x;
  const int swz = (lin & 7) * 32 + (lin >> 3);
  const int m0 = (swz >> 3) * 128, n0 = (swz & 7) * 128;
  __shared__ unsigned short As[128 * 64];
  __shared__ unsigned short Ws[128 * 64];
  const int t = threadIdx.x, wave = t >> 6, lane = t & 63;
  const int wr = wave >> 1, wc = wave & 1;
  floatx4 acc[4][4];
  const floatx4 z4 = {0.f, 0.f, 0.f, 0.f};
#pragma unroll
  for (int i = 0; i < 4; ++i)
#pragma unroll
    for (int j = 0; j < 4; ++j) acc[i][j] = z4;

  for (int k0 = 0; k0 < 1024; k0 += 64) {
    stage_tile<16>(A + (size_t)m0 * 1024 + k0, As, wave, lane);
    stage_tile<16>(W + (size_t)n0 * 1024 + k0, Ws, wave, lane);
    __syncthreads();
#pragma unroll
    for (int ks = 0; ks < 2; ++ks) {
      const int kb = ks * 64 + ((lane >> 4) << 4);
      bhalf8 af[4], bf[4];
#pragma unroll
      for (int mi = 0; mi < 4; ++mi)
        af[mi] = read_frag(As, wr * 64 + mi * 16 + (lane & 15), kb);
#pragma unroll
      for (int ni = 0; ni < 4; ++ni)
        bf[ni] = read_frag(Ws, wc * 64 + ni * 16 + (lane & 15), kb);
#pragma unroll
      for (int mi = 0; mi < 4; ++mi)
#pragma unroll
        for (int ni = 0; ni < 4; ++ni)
          acc[mi][ni] = __builtin_amdgcn_mfma_f32_16x16x32_bf16(af[mi], bf[ni], acc[mi][ni], 0, 0, 0);
    }
    __syncthreads();
  }
#pragma unroll
  for (int mi = 0; mi < 4; ++mi)
#pragma unroll
    for (int ni = 0; ni < 4; ++ni) {
      const int col = n0 + wc * 64 + ni * 16 + (lane & 15);
      const float bv = bias[col];
#pragma unroll
      for (int r = 0; r < 4; ++r) {
        const int row = m0 + wr * 64 + mi * 16 + (lane >> 4) * 4 + r;
        const float v = acc[mi][ni][r] + bv;
        if (BF16OUT)
          ((unsigned short*)C)[(size_t)row * 1024 + col] = f2bf(v);
        else
          ((float*)C)[(size_t)row * 1024 + col] = v;
      }
    }
}

// ---------------------------------------------------------------------------
// In-place RoPE on bf16 [B,S,E]; one thread per channel pair.
// ---------------------------------------------------------------------------
__global__ __launch_bounds__(256) void rope_bf_kernel(unsigned int* __restrict__ X,
                                                      const int* __restrict__ idxs) {
  const int gid = blockIdx.x * 256 + threadIdx.x;
  const int i = gid & 511, bs = gid >> 9;
  const int pos = idxs[bs];
  const double freq = exp(-(double)(2 * i) * (9.210340371976184 / 1024.0));
  const double ang = fmod((double)pos * freq, 6.283185307179586476925287);
  const float fa = (float)ang;
  float sn, c;
  sincosf(fa, &sn, &c);
  const unsigned v = X[gid];
  const float x = bf2f((unsigned short)(v & 0xffffu));
  const float y = bf2f((unsigned short)(v >> 16));
  const float rx = x * c - y * sn;
  const float ry = x * sn + y * c;
  X[gid] = (unsigned)f2bf(rx) | ((unsigned)f2bf(ry) << 16);
}

// ---------------------------------------------------------------------------
// Vt[(b*16+h)*64 + d][s] = Vr[b][s][h*64+d]   (bf16 transpose, 64x64 tiles)
// ---------------------------------------------------------------------------
__global__ __launch_bounds__(256) void transpose_v_kernel(
    const unsigned short* __restrict__ Vr, unsigned short* __restrict__ Vt) {
  const int s0 = blockIdx.x * 64;
  const int bh = blockIdx.y;
  const int b = bh >> 4, h = bh & 15;
  __shared__ unsigned short L[64][72];
  const int t = threadIdx.x, r = t >> 2, cq = (t & 3) * 16;
  const unsigned short* src = Vr + ((size_t)(b * S_) + s0 + r) * E_ + h * HD_ + cq;
  *(bhalf8*)&L[r][cq] = *(const bhalf8*)src;
  *(bhalf8*)&L[r][cq + 8] = *(const bhalf8*)(src + 8);
  __syncthreads();
  bhalf8 o0, o1;
#pragma unroll
  for (int u = 0; u < 8; ++u) o0[u] = (short)L[cq + u][r];
#pragma unroll
  for (int u = 0; u < 8; ++u) o1[u] = (short)L[cq + 8 + u][r];
  unsigned short* dst = Vt + ((size_t)bh * 64 + r) * 1024 + s0 + cq;
  *(bhalf8*)dst = o0;
  *(bhalf8*)(dst + 8) = o1;
}

// ---------------------------------------------------------------------------
// Fused scores+softmax. One block per (32 q-rows, head-batch).
// Phase 1: QK^T with Q/K fragments loaded straight from global (L2-hot),
//          full S row (1024) in 128 acc VGPRs per thread.
// Phase 2: acc -> XOR-swizzled f16 LDS buffer; per-row masked softmax with
//          coalesced mask loads; writes bf16 P to global.
// ---------------------------------------------------------------------------
__global__ __launch_bounds__(256) void fused_sm_kernel(
    const unsigned short* __restrict__ Qr, const unsigned short* __restrict__ Kr,
    unsigned short* __restrict__ P, const void* __restrict__ amask,
    const void* __restrict__ kpm, const int* __restrict__ flagp, int hb0) {
  const int lhb = blockIdx.y, hb = hb0 + lhb;
  const int h = hb >> 2, b = hb & 3, bp = hb >> 4;
  const int q0 = blockIdx.x * 32;
  __shared__ unsigned short Sbuf[32 * 1024];  // f16 bits, XOR-swizzled rows
  const int t = threadIdx.x, w = t >> 6, lane = t & 63;
  const int l4 = lane >> 4, l15 = lane & 15;

  const char* Qbase = (const char*)(Qr + ((size_t)b << 20)) + h * 128;
  const char* Kbase = (const char*)(Kr + ((size_t)b << 20)) + h * 128;

  // Q fragments (held for all k): aq[qtile][kstep]
  bhalf8 aq[2][2];
#pragma unroll
  for (int qt = 0; qt < 2; ++qt)
#pragma unroll
    for (int ks = 0; ks < 2; ++ks)
      aq[qt][ks] = *(const bhalf8*)(Qbase + (size_t)(q0 + qt * 16 + l15) * 2048 +
                                    ks * 64 + l4 * 16);

  floatx4 acc[2][16];
  const floatx4 z4 = {0.f, 0.f, 0.f, 0.f};
#pragma unroll
  for (int qt = 0; qt < 2; ++qt)
#pragma unroll
    for (int kt = 0; kt < 16; ++kt) acc[qt][kt] = z4;

  const int kcol0 = w * 256;
#pragma unroll
  for (int kt = 0; kt < 16; ++kt) {
    const char* kb = Kbase + (size_t)(kcol0 + kt * 16 + l15) * 2048 + l4 * 16;
    bhalf8 b0 = *(const bhalf8*)kb;
    bhalf8 b1 = *(const bhalf8*)(kb + 64);
    acc[0][kt] = __builtin_amdgcn_mfma_f32_16x16x32_bf16(aq[0][0], b0, acc[0][kt], 0, 0, 0);
    acc[1][kt] = __builtin_amdgcn_mfma_f32_16x16x32_bf16(aq[1][0], b0, acc[1][kt], 0, 0, 0);
    acc[0][kt] = __builtin_amdgcn_mfma_f32_16x16x32_bf16(aq[0][1], b1, acc[0][kt], 0, 0, 0);
    acc[1][kt] = __builtin_amdgcn_mfma_f32_16x16x32_bf16(aq[1][1], b1, acc[1][kt], 0, 0, 0);
  }

  // acc -> Sbuf (f16, scaled by 1/8). value = S[q][k], q local.
#pragma unroll
  for (int qt = 0; qt < 2; ++qt)
#pragma unroll
    for (int kt = 0; kt < 16; ++kt) {
      const int k = kcol0 + kt * 16 + l15;
#pragma unroll
      for (int r = 0; r < 4; ++r) {
        const int q = qt * 16 + l4 * 4 + r;
        const int off = q * 2048 + ((k * 2) ^ ((q & 7) << 4));
        *(unsigned short*)((char*)Sbuf + off) = f2h(acc[qt][kt][r] * 0.125f);
      }
    }
  __syncthreads();

  // Softmax: wave w handles local rows [w*8, w*8+8). Lane's k-set: j*256+lane*4+c
  const int isu8 = *flagp;
  bool km[16];
  if (isu8) {
    const uint8_t* kp = (const uint8_t*)kpm + (size_t)bp * 1024;
#pragma unroll
    for (int j = 0; j < 4; ++j) {
      uchar4 v = *(const uchar4*)(kp + j * 256 + lane * 4);
      km[j * 4 + 0] = v.x != 0; km[j * 4 + 1] = v.y != 0;
      km[j * 4 + 2] = v.z != 0; km[j * 4 + 3] = v.w != 0;
    }
  } else {
    const int* kp = (const int*)kpm + (size_t)bp * 1024;
#pragma unroll
    for (int j = 0; j < 4; ++j) {
      int4 v = *(const int4*)(kp + j * 256 + lane * 4);
      km[j * 4 + 0] = v.x != 0; km[j * 4 + 1] = v.y != 0;
      km[j * 4 + 2] = v.z != 0; km[j * 4 + 3] = v.w != 0;
    }
  }

  for (int rr = 0; rr < 8; ++rr) {
    const int q = w * 8 + rr;        // local row
    const int gq = q0 + q;           // global q (for masks / output)
    const int xorv = (q & 7) << 4;
    float x[16];
#pragma unroll
    for (int j = 0; j < 4; ++j) {
      const int off = q * 2048 + ((j * 512 + lane * 8) ^ xorv);
      ushort4 hv = *(const ushort4*)((const char*)Sbuf + off);
      x[j * 4 + 0] = h2f(hv.x); x[j * 4 + 1] = h2f(hv.y);
      x[j * 4 + 2] = h2f(hv.z); x[j * 4 + 3] = h2f(hv.w);
    }
    if (isu8) {
      const uint8_t* ap = (const uint8_t*)amask + (size_t)gq * 1024;
#pragma unroll
      for (int j = 0; j < 4; ++j) {
        uchar4 v = *(const uchar4*)(ap + j * 256 + lane * 4);
        if (v.x | km[j * 4 + 0]) x[j * 4 + 0] = -INFINITY;
        if (v.y | km[j * 4 + 1]) x[j * 4 + 1] = -INFINITY;
        if (v.z | km[j * 4 + 2]) x[j * 4 + 2] = -INFINITY;
        if (v.w | km[j * 4 + 3]) x[j * 4 + 3] = -INFINITY;
      }
    } else {
      const int* ap = (const int*)amask + (size_t)gq * 1024;
#pragma unroll
      for (int j = 0; j < 4; ++j) {
        int4 v = *(const int4*)(ap + j * 256 + lane * 4);
        if (v.x || km[j * 4 + 0]) x[j * 4 + 0] = -INFINITY;
        if (v.y || km[j * 4 + 1]) x[j * 4 + 1] = -INFINITY;
        if (v.z || km[j * 4 + 2]) x[j * 4 + 2] = -INFINITY;
        if (v.w || km[j * 4 + 3]) x[j * 4 + 3] = -INFINITY;
      }
    }
    float m = -INFINITY;
#pragma unroll
    for (int i = 0; i < 16; ++i) m = fmaxf(m, x[i]);
    for (int o = 32; o > 0; o >>= 1) m = fmaxf(m, __shfl_xor(m, o));
    float s = 0.f;
#pragma unroll
    for (int i = 0; i < 16; ++i) { x[i] = expf(x[i] - m); s += x[i]; }
    for (int o = 32; o > 0; o >>= 1) s += __shfl_xor(s, o);
    const float inv = 1.0f / s;
    unsigned short* prow = P + ((size_t)lhb << 20) + (size_t)gq * 1024;
#pragma unroll
    for (int j = 0; j < 4; ++j) {
      ushort4 w4;
      w4.x = f2bf(x[j * 4 + 0] * inv); w4.y = f2bf(x[j * 4 + 1] * inv);
      w4.z = f2bf(x[j * 4 + 2] * inv); w4.w = f2bf(x[j * 4 + 3] * inv);
      *(ushort4*)(prow + j * 256 + lane * 4) = w4;
    }
  }
}

// ---------------------------------------------------------------------------
// outW[b][q][k] += (1/16) * sum_hh P[hh*4+b][q][k]   (this chunk's heads)
// ---------------------------------------------------------------------------
__global__ __launch_bounds__(256) void wmean_kernel(
    const unsigned short* __restrict__ P, float* __restrict__ outW,
    int nhh, int first) {
  const size_t gid = (size_t)blockIdx.x * 256 + threadIdx.x;  // one per 8 k
  const int k8 = (int)(gid & 127);
  const int q = (int)((gid >> 7) & 1023);
  const int b = (int)(gid >> 17);
  float s[8];
#pragma unroll
  for (int u = 0; u < 8; ++u) s[u] = 0.f;
  for (int hh = 0; hh < nhh; ++hh) {
    const int lhb = hh * 4 + b;
    bhalf8 v = *(const bhalf8*)(P + ((size_t)lhb << 20) + ((size_t)q << 10) + k8 * 8);
#pragma unroll
    for (int u = 0; u < 8; ++u) s[u] += bf2f((unsigned short)v[u]);
  }
  float* o = outW + (((size_t)(b * S_ + q)) << 10) + k8 * 8;
  const float invH = 1.0f / 16.0f;
  float4 v0, v1;
  v0.x = s[0] * invH; v0.y = s[1] * invH; v0.z = s[2] * invH; v0.w = s[3] * invH;
  v1.x = s[4] * invH; v1.y = s[5] * invH; v1.z = s[6] * invH; v1.w = s[7] * invH;
  if (!first) {
    float4 a = *(float4*)o, b4 = *(float4*)(o + 4);
    v0.x += a.x; v0.y += a.y; v0.z += a.z; v0.w += a.w;
    v1.x += b4.x; v1.y += b4.y; v1.z += b4.z; v1.w += b4.w;
  }
  *(float4*)o = v0;
  *(float4*)(o + 4) = v1;
}

// ---------------------------------------------------------------------------
// PV: Ocat[b][q][h*64+d] = sum_k P[lhb][q][k] * Vt[bh*64+d][k]
// 64q x 64d per block, BK=64, 4 waves in 2x2. grid (16 qtiles, CH)
// ---------------------------------------------------------------------------
__global__ __launch_bounds__(256) void pv_mfma_kernel(
    const unsigned short* __restrict__ Wt, const unsigned short* __restrict__ Vt,
    unsigned short* __restrict__ Ocat, int hb0) {
  const int lhb = blockIdx.y, hb = hb0 + lhb;
  const int h = hb >> 2, b = hb & 3;
  const int q0 = blockIdx.x * 64;
  __shared__ unsigned short Ps[64 * 64];
  __shared__ unsigned short Vs[64 * 64];
  const int t = threadIdx.x, wave = t >> 6, lane = t & 63;
  const int wr = wave >> 1, wc = wave & 1;
  const unsigned short* Wh = Wt + ((size_t)lhb << 20);
  const unsigned short* Vh = Vt + (size_t)(b * 16 + h) * 65536;
  floatx4 acc[2][2];
  const floatx4 z4 = {0.f, 0.f, 0.f, 0.f};
#pragma unroll
  for (int i = 0; i < 2; ++i)
#pragma unroll
    for (int j = 0; j < 2; ++j) acc[i][j] = z4;

  for (int k0 = 0; k0 < 1024; k0 += 64) {
    stage_tile<8>(Wh + (size_t)q0 * 1024 + k0, Ps, wave, lane);
    stage_tile<8>(Vh + k0, Vs, wave, lane);
    __syncthreads();
#pragma unroll
    for (int ks = 0; ks < 2; ++ks) {
      const int kb = ks * 64 + ((lane >> 4) << 4);
      bhalf8 af[2], bf[2];
#pragma unroll
      for (int mi = 0; mi < 2; ++mi)
        af[mi] = read_frag(Ps, wr * 32 + mi * 16 + (lane & 15), kb);
#pragma unroll
      for (int ni = 0; ni < 2; ++ni)
        bf[ni] = read_frag(Vs, wc * 32 + ni * 16 + (lane & 15), kb);
#pragma unroll
      for (int mi = 0; mi < 2; ++mi)
#pragma unroll
        for (int ni = 0; ni < 2; ++ni)
          acc[mi][ni] = __builtin_amdgcn_mfma_f32_16x16x32_bf16(af[mi], bf[ni], acc[mi][ni], 0, 0, 0);
    }
    __syncthreads();
  }
#pragma unroll
  for (int mi = 0; mi < 2; ++mi)
#pragma unroll
    for (int ni = 0; ni < 2; ++ni) {
      const int d = wc * 32 + ni * 16 + (lane & 15);
#pragma unroll
      for (int r = 0; r < 4; ++r) {
        const int q = q0 + wr * 32 + mi * 16 + (lane >> 4) * 4 + r;
        Ocat[((size_t)(b * S_) + q) * E_ + h * HD_ + d] = f2bf(acc[mi][ni][r]);
      }
    }
}

// ---------------------------------------------------------------------------
extern "C" void kernel_launch(void* const* d_in, const int* in_sizes, int n_in,
                              void* d_out, int out_size, void* d_ws, size_t ws_size,
                              hipStream_t stream) {
  (void)in_sizes; (void)n_in; (void)out_size;
  const float* query = (const float*)d_in[0];
  const float* key   = (const float*)d_in[1];
  const float* value = (const float*)d_in[2];
  const int* qidx = (const int*)d_in[3];
  const int* kidx = (const int*)d_in[4];
  const void* amask = d_in[5];
  const void* kpm   = d_in[6];
  const float* Wq = (const float*)d_in[7];
  const float* bq = (const float*)d_in[8];
  const float* Wk = (const float*)d_in[9];
  const float* bk = (const float*)d_in[10];
  const float* Wv = (const float*)d_in[11];
  const float* bv = (const float*)d_in[12];
  const float* Wo = (const float*)d_in[13];
  const float* bo = (const float*)d_in[14];

  float* outA = (float*)d_out;                          // [B,S,E] fp32
  float* outW = (float*)d_out + (size_t)B_ * S_ * E_;   // [B,S,S] fp32

  float* ws = (float*)d_ws;
  unsigned short* Ab   = (unsigned short*)(ws + 0);         // 3x 4,194,304 bf16
  unsigned short* Wb   = (unsigned short*)(ws + 6291456);   // 4x 1,048,576 bf16
  unsigned short* Qr   = (unsigned short*)(ws + 8388608);
  unsigned short* Kr   = (unsigned short*)(ws + 10485760);
  unsigned short* Vr   = (unsigned short*)(ws + 12582912);
  unsigned short* Vt   = (unsigned short*)(ws + 14680064);
  unsigned short* Ocat = (unsigned short*)(ws + 16777216);
  int* flagp           = (int*)(ws + 18874368);
  const size_t tail_off = 18874432;  // floats

  // P chunk: per head-batch 1024*1024 bf16 = 524288 floats.
  const size_t ws_floats = ws_size / 4;
  int CH = 0;
  unsigned short* P = nullptr;
  for (int c = 64; c >= 4; c >>= 1) {
    if (tail_off + (size_t)c * 524288 <= ws_floats) {
      CH = c;
      P = (unsigned short*)(ws + tail_off);
      break;
    }
  }
  if (!CH) {  // alias the Ab region (dead after the QKV GEMM): 6.29M floats >= 8 planes
    CH = 8;
    P = (unsigned short*)ws;
  }

  detect_bool_kernel<<<1, 64, 0, stream>>>((const uint8_t*)amask, flagp);

  cvt_in_kernel<<<dim3(2048, 1, 3), 256, 0, stream>>>(query, key, value, Ab);
  cvt_w_kernel<<<dim3(512, 1, 4), 256, 0, stream>>>(Wq, Wk, Wv, Wo, Wb);

  mfma_gemm_kernel<true><<<dim3(8, 32, 3), 256, 0, stream>>>(
      Ab, Ab + 4194304, Ab + 8388608,
      Wb, Wb + 1048576, Wb + 2097152,
      bq, bk, bv, Qr, Kr, Vr);

  rope_bf_kernel<<<8192, 256, 0, stream>>>((unsigned int*)Qr, qidx);
  rope_bf_kernel<<<8192, 256, 0, stream>>>((unsigned int*)Kr, kidx);

  transpose_v_kernel<<<dim3(16, 64), 256, 0, stream>>>(Vr, Vt);

  const int nch = HB_ / CH;
  for (int c = 0; c < nch; ++c) {
    const int hb0 = c * CH;
    fused_sm_kernel<<<dim3(32, CH), 256, 0, stream>>>(Qr, Kr, P, amask, kpm,
                                                      flagp, hb0);
    wmean_kernel<<<2048, 256, 0, stream>>>(P, outW, CH / 4, (c == 0) ? 1 : 0);
    pv_mfma_kernel<<<dim3(16, CH), 256, 0, stream>>>(P, Vt, Ocat, hb0);
  }

  mfma_gemm_kernel<false><<<dim3(8, 32, 1), 256, 0, stream>>>(
      Ocat, Ocat, Ocat, Wb + 3145728, Wb + 3145728, Wb + 3145728,
      bo, bo, bo, outA, outA, outA);
}

// Round 4
// 255.480 us; speedup vs baseline: 5.9890x; 1.0620x over previous
//
#include <hip/hip_runtime.h>
#include <stdint.h>
#include <math.h>

#define B_ 4
#define S_ 1024
#define E_ 1024
#define H_ 16
#define HD_ 64
#define HB_ 64  // H_*B_

typedef __attribute__((ext_vector_type(8))) short bhalf8;
typedef __attribute__((ext_vector_type(4))) float floatx4;

__device__ __forceinline__ unsigned short f2bf(float f) {
  union { float f; unsigned u; } v; v.f = f;
  unsigned r = (v.u + 0x7FFFu + ((v.u >> 16) & 1u)) >> 16;
  return (unsigned short)r;
}
__device__ __forceinline__ float bf2f(unsigned short b) {
  union { unsigned u; float f; } v; v.u = ((unsigned)b) << 16;
  return v.f;
}
__device__ __forceinline__ unsigned short f2h(float f) {
  union { _Float16 h; unsigned short u; } v; v.h = (_Float16)f; return v.u;
}
__device__ __forceinline__ float h2f(unsigned short u) {
  union { unsigned short u; _Float16 h; } v; v.u = u; return (float)v.h;
}

__device__ __forceinline__ void gload16(const void* g, void* l) {
  __builtin_amdgcn_global_load_lds(
      (const __attribute__((address_space(1))) unsigned int*)g,
      (__attribute__((address_space(3))) unsigned int*)l, 16, 0, 0);
}

// Stage NCH*8 rows x 64 bf16 (128B rows, global row stride 1024 elems) into
// LDS, linear dest + inverse-swizzled source (involution: byte ^= (row&7)<<4).
template <int NCH>
__device__ __forceinline__ void stage_tile(const unsigned short* org,
                                           unsigned short* lds, int wave, int lane) {
  const int rl = lane >> 3;                      // row within 8-row chunk
  const int scb = ((lane & 7) << 4) ^ (rl << 4); // pre-swizzled source col byte
  const char* base = (const char*)org + scb;
#pragma unroll
  for (int i = 0; i < NCH / 4; ++i) {
    const int c = wave + 4 * i;
    gload16(base + (size_t)(c * 8 + rl) * 2048, (char*)lds + c * 1024);
  }
}

// Read one MFMA operand fragment (8 contiguous bf16) with the matching swizzle.
__device__ __forceinline__ bhalf8 read_frag(const unsigned short* lds, int row, int kbyte) {
  const int off = row * 128 + (kbyte ^ ((row & 7) << 4));
  return *(const bhalf8*)((const char*)lds + off);
}

// ---------------------------------------------------------------------------
__global__ void detect_bool_kernel(const uint8_t* __restrict__ amask, int* __restrict__ flag) {
  if (threadIdx.x == 0 && blockIdx.x == 0) *flag = (amask[1] != 0) ? 1 : 0;
}

// fp32 -> bf16 for the 3 activation inputs (z selects tensor)
__global__ __launch_bounds__(256) void cvt_in_kernel(
    const float* __restrict__ q, const float* __restrict__ k,
    const float* __restrict__ v, unsigned short* __restrict__ Ab) {
  const int z = blockIdx.z;
  const float* src = (z == 0) ? q : (z == 1) ? k : v;
  unsigned short* dst = Ab + (size_t)z * 4194304;
  const size_t i = ((size_t)blockIdx.x * 256 + threadIdx.x) * 8;
  float4 a = *(const float4*)(src + i);
  float4 b = *(const float4*)(src + i + 4);
  bhalf8 r;
  r[0] = (short)f2bf(a.x); r[1] = (short)f2bf(a.y);
  r[2] = (short)f2bf(a.z); r[3] = (short)f2bf(a.w);
  r[4] = (short)f2bf(b.x); r[5] = (short)f2bf(b.y);
  r[6] = (short)f2bf(b.z); r[7] = (short)f2bf(b.w);
  *(bhalf8*)(dst + i) = r;
}

// fp32 -> bf16 for the 4 weight matrices
__global__ __launch_bounds__(256) void cvt_w_kernel(
    const float* __restrict__ wq, const float* __restrict__ wk,
    const float* __restrict__ wv, const float* __restrict__ wo,
    unsigned short* __restrict__ Wb) {
  const int z = blockIdx.z;
  const float* src = (z == 0) ? wq : (z == 1) ? wk : (z == 2) ? wv : wo;
  unsigned short* dst = Wb + (size_t)z * 1048576;
  const size_t i = ((size_t)blockIdx.x * 256 + threadIdx.x) * 8;
  float4 a = *(const float4*)(src + i);
  float4 b = *(const float4*)(src + i + 4);
  bhalf8 r;
  r[0] = (short)f2bf(a.x); r[1] = (short)f2bf(a.y);
  r[2] = (short)f2bf(a.z); r[3] = (short)f2bf(a.w);
  r[4] = (short)f2bf(b.x); r[5] = (short)f2bf(b.y);
  r[6] = (short)f2bf(b.z); r[7] = (short)f2bf(b.w);
  *(bhalf8*)(dst + i) = r;
}

// ---------------------------------------------------------------------------
// C[4096,1024] = A @ W^T + bias. 128x128 tile, BK=64, 4 waves (2x2 quadrants).
// XCD-chunked swizzle on the 256-block (x,y) grid for L2 locality.
// ---------------------------------------------------------------------------
template <bool BF16OUT>
__global__ __launch_bounds__(256) void mfma_gemm_kernel(
    const unsigned short* __restrict__ A0, const unsigned short* __restrict__ A1,
    const unsigned short* __restrict__ A2,
    const unsigned short* __restrict__ W0, const unsigned short* __restrict__ W1,
    const unsigned short* __restrict__ W2,
    const float* __restrict__ b0, const float* __restrict__ b1,
    const float* __restrict__ b2,
    void* __restrict__ C0, void* __restrict__ C1, void* __restrict__ C2) {
  const int z = blockIdx.z;
  const unsigned short* A = (z == 0) ? A0 : (z == 1) ? A1 : A2;
  const unsigned short* W = (z == 0) ? W0 : (z == 1) ? W1 : W2;
  const float* bias = (z == 0) ? b0 : (z == 1) ? b1 : b2;
  void* C = (z == 0) ? C0 : (z == 1) ? C1 : C2;
  const int lin = blockIdx.y * 8 + blockIdx.x;
  const int swz = (lin & 7) * 32 + (lin >> 3);
  const int m0 = (swz >> 3) * 128, n0 = (swz & 7) * 128;
  __shared__ unsigned short As[128 * 64];
  __shared__ unsigned short Ws[128 * 64];
  const int t = threadIdx.x, wave = t >> 6, lane = t & 63;
  const int wr = wave >> 1, wc = wave & 1;
  floatx4 acc[4][4];
  const floatx4 z4 = {0.f, 0.f, 0.f, 0.f};
#pragma unroll
  for (int i = 0; i < 4; ++i)
#pragma unroll
    for (int j = 0; j < 4; ++j) acc[i][j] = z4;

  for (int k0 = 0; k0 < 1024; k0 += 64) {
    stage_tile<16>(A + (size_t)m0 * 1024 + k0, As, wave, lane);
    stage_tile<16>(W + (size_t)n0 * 1024 + k0, Ws, wave, lane);
    __syncthreads();
#pragma unroll
    for (int ks = 0; ks < 2; ++ks) {
      const int kb = ks * 64 + ((lane >> 4) << 4);
      bhalf8 af[4], bf[4];
#pragma unroll
      for (int mi = 0; mi < 4; ++mi)
        af[mi] = read_frag(As, wr * 64 + mi * 16 + (lane & 15), kb);
#pragma unroll
      for (int ni = 0; ni < 4; ++ni)
        bf[ni] = read_frag(Ws, wc * 64 + ni * 16 + (lane & 15), kb);
#pragma unroll
      for (int mi = 0; mi < 4; ++mi)
#pragma unroll
        for (int ni = 0; ni < 4; ++ni)
          acc[mi][ni] = __builtin_amdgcn_mfma_f32_16x16x32_bf16(af[mi], bf[ni], acc[mi][ni], 0, 0, 0);
    }
    __syncthreads();
  }
#pragma unroll
  for (int mi = 0; mi < 4; ++mi)
#pragma unroll
    for (int ni = 0; ni < 4; ++ni) {
      const int col = n0 + wc * 64 + ni * 16 + (lane & 15);
      const float bv = bias[col];
#pragma unroll
      for (int r = 0; r < 4; ++r) {
        const int row = m0 + wr * 64 + mi * 16 + (lane >> 4) * 4 + r;
        const float v = acc[mi][ni][r] + bv;
        if (BF16OUT)
          ((unsigned short*)C)[(size_t)row * 1024 + col] = f2bf(v);
        else
          ((float*)C)[(size_t)row * 1024 + col] = v;
      }
    }
}

// ---------------------------------------------------------------------------
// In-place RoPE on bf16 [B,S,E]; one thread per channel pair.
// ---------------------------------------------------------------------------
__global__ __launch_bounds__(256) void rope_bf_kernel(unsigned int* __restrict__ X,
                                                      const int* __restrict__ idxs) {
  const int gid = blockIdx.x * 256 + threadIdx.x;
  const int i = gid & 511, bs = gid >> 9;
  const int pos = idxs[bs];
  const double freq = exp(-(double)(2 * i) * (9.210340371976184 / 1024.0));
  const double ang = fmod((double)pos * freq, 6.283185307179586476925287);
  const float fa = (float)ang;
  float sn, c;
  sincosf(fa, &sn, &c);
  const unsigned v = X[gid];
  const float x = bf2f((unsigned short)(v & 0xffffu));
  const float y = bf2f((unsigned short)(v >> 16));
  const float rx = x * c - y * sn;
  const float ry = x * sn + y * c;
  X[gid] = (unsigned)f2bf(rx) | ((unsigned)f2bf(ry) << 16);
}

// ---------------------------------------------------------------------------
// Vt[(b*16+h)*64 + d][s] = Vr[b][s][h*64+d]   (bf16 transpose, 64x64 tiles)
// ---------------------------------------------------------------------------
__global__ __launch_bounds__(256) void transpose_v_kernel(
    const unsigned short* __restrict__ Vr, unsigned short* __restrict__ Vt) {
  const int s0 = blockIdx.x * 64;
  const int bh = blockIdx.y;
  const int b = bh >> 4, h = bh & 15;
  __shared__ unsigned short L[64][72];
  const int t = threadIdx.x, r = t >> 2, cq = (t & 3) * 16;
  const unsigned short* src = Vr + ((size_t)(b * S_) + s0 + r) * E_ + h * HD_ + cq;
  *(bhalf8*)&L[r][cq] = *(const bhalf8*)src;
  *(bhalf8*)&L[r][cq + 8] = *(const bhalf8*)(src + 8);
  __syncthreads();
  bhalf8 o0, o1;
#pragma unroll
  for (int u = 0; u < 8; ++u) o0[u] = (short)L[cq + u][r];
#pragma unroll
  for (int u = 0; u < 8; ++u) o1[u] = (short)L[cq + 8 + u][r];
  unsigned short* dst = Vt + ((size_t)bh * 64 + r) * 1024 + s0 + cq;
  *(bhalf8*)dst = o0;
  *(bhalf8*)(dst + 8) = o1;
}

// ---------------------------------------------------------------------------
// Fused scores+softmax v2. One block per (16 q-rows, head-batch).
// Phase 1: swapped-operand QK^T  (D[m=k, n=q]) with K fragments straight from
//          global (L2-resident). Lane's 4 acc regs are contiguous in k ->
//          packed ds_write_b64 spills of raw f16 S into 32KB swizzled LDS.
// Phase 2: per-row masked softmax, native exp2 with folded scale, bf16 P out.
// ---------------------------------------------------------------------------
__global__ __launch_bounds__(256) void fused_sm_kernel(
    const unsigned short* __restrict__ Qr, const unsigned short* __restrict__ Kr,
    unsigned short* __restrict__ P, const void* __restrict__ amask,
    const void* __restrict__ kpm, const int* __restrict__ flagp, int hb0) {
  const int lhb = blockIdx.y, hb = hb0 + lhb;
  const int h = hb >> 2, b = hb & 3, bp = hb >> 4;
  const int q0 = blockIdx.x * 16;
  __shared__ unsigned short Sbuf[16 * 1024];  // f16 raw S, XOR-swizzled rows
  const int t = threadIdx.x, w = t >> 6, lane = t & 63;
  const int l4 = lane >> 4, l15 = lane & 15;

  const char* Qbase = (const char*)(Qr + ((size_t)b << 20)) + h * 128;
  const char* Kbase = (const char*)(Kr + ((size_t)b << 20)) + h * 128;

  // B-operand: Q fragments for rows q0 + l15 (held for all k)
  bhalf8 bq0 = *(const bhalf8*)(Qbase + (size_t)(q0 + l15) * 2048 + l4 * 16);
  bhalf8 bq1 = *(const bhalf8*)(Qbase + (size_t)(q0 + l15) * 2048 + 64 + l4 * 16);

  floatx4 acc[16];
  const floatx4 z4 = {0.f, 0.f, 0.f, 0.f};
#pragma unroll
  for (int i = 0; i < 16; ++i) acc[i] = z4;

  const int krow0 = w * 256;  // this wave's 256 k-columns
#pragma unroll
  for (int mt = 0; mt < 16; ++mt) {
    const char* kr = Kbase + (size_t)(krow0 + mt * 16 + l15) * 2048 + l4 * 16;
    bhalf8 a0 = *(const bhalf8*)kr;
    bhalf8 a1 = *(const bhalf8*)(kr + 64);
    acc[mt] = __builtin_amdgcn_mfma_f32_16x16x32_bf16(a0, bq0, acc[mt], 0, 0, 0);
    acc[mt] = __builtin_amdgcn_mfma_f32_16x16x32_bf16(a1, bq1, acc[mt], 0, 0, 0);
  }

  // Spill raw S to LDS as f16: lane owns q=l15, k = krow0 + mt*16 + l4*4 + r.
  {
    const int q = l15;
    const int xorv = (q & 7) << 4;
#pragma unroll
    for (int mt = 0; mt < 16; ++mt) {
      const int kb2 = (krow0 + mt * 16 + l4 * 4) * 2;  // byte offset of k
      ushort4 hv;
      hv.x = f2h(acc[mt][0]); hv.y = f2h(acc[mt][1]);
      hv.z = f2h(acc[mt][2]); hv.w = f2h(acc[mt][3]);
      *(ushort4*)((char*)Sbuf + q * 2048 + (kb2 ^ xorv)) = hv;
    }
  }
  __syncthreads();

  // Phase 2. Lane's k-set per row: k = j*512 + lane*8 + u, j=0..1, u=0..7.
  const int isu8 = *flagp;
  bool km[16];
  if (isu8) {
    const uint8_t* kp = (const uint8_t*)kpm + (size_t)bp * 1024;
#pragma unroll
    for (int j = 0; j < 2; ++j) {
      uint2 mv = *(const uint2*)(kp + j * 512 + lane * 8);
#pragma unroll
      for (int u = 0; u < 4; ++u) {
        km[j * 8 + u] = ((mv.x >> (8 * u)) & 0xffu) != 0;
        km[j * 8 + 4 + u] = ((mv.y >> (8 * u)) & 0xffu) != 0;
      }
    }
  } else {
    const int* kp = (const int*)kpm + (size_t)bp * 1024;
#pragma unroll
    for (int j = 0; j < 2; ++j) {
      int4 v0 = *(const int4*)(kp + j * 512 + lane * 8);
      int4 v1 = *(const int4*)(kp + j * 512 + lane * 8 + 4);
      km[j * 8 + 0] = v0.x != 0; km[j * 8 + 1] = v0.y != 0;
      km[j * 8 + 2] = v0.z != 0; km[j * 8 + 3] = v0.w != 0;
      km[j * 8 + 4] = v1.x != 0; km[j * 8 + 5] = v1.y != 0;
      km[j * 8 + 6] = v1.z != 0; km[j * 8 + 7] = v1.w != 0;
    }
  }

  const float C = 0.18033688011112042f;  // 0.125 * log2(e)
  for (int rr = 0; rr < 4; ++rr) {
    const int ql = w * 4 + rr;
    const int gq = q0 + ql;
    const int xr = (ql & 7) << 4;
    float x[16];
#pragma unroll
    for (int j = 0; j < 2; ++j) {
      const int off = ql * 2048 + ((j * 1024 + lane * 16) ^ xr);
      bhalf8 hv = *(const bhalf8*)((const char*)Sbuf + off);
#pragma unroll
      for (int u = 0; u < 8; ++u) x[j * 8 + u] = h2f((unsigned short)hv[u]);
    }
    if (isu8) {
      const uint8_t* ap = (const uint8_t*)amask + (size_t)gq * 1024;
#pragma unroll
      for (int j = 0; j < 2; ++j) {
        uint2 mv = *(const uint2*)(ap + j * 512 + lane * 8);
#pragma unroll
        for (int u = 0; u < 4; ++u) {
          if (((mv.x >> (8 * u)) & 0xffu) || km[j * 8 + u]) x[j * 8 + u] = -INFINITY;
          if (((mv.y >> (8 * u)) & 0xffu) || km[j * 8 + 4 + u]) x[j * 8 + 4 + u] = -INFINITY;
        }
      }
    } else {
      const int* ap = (const int*)amask + (size_t)gq * 1024;
#pragma unroll
      for (int j = 0; j < 2; ++j) {
        int4 v0 = *(const int4*)(ap + j * 512 + lane * 8);
        int4 v1 = *(const int4*)(ap + j * 512 + lane * 8 + 4);
        if (v0.x || km[j * 8 + 0]) x[j * 8 + 0] = -INFINITY;
        if (v0.y || km[j * 8 + 1]) x[j * 8 + 1] = -INFINITY;
        if (v0.z || km[j * 8 + 2]) x[j * 8 + 2] = -INFINITY;
        if (v0.w || km[j * 8 + 3]) x[j * 8 + 3] = -INFINITY;
        if (v1.x || km[j * 8 + 4]) x[j * 8 + 4] = -INFINITY;
        if (v1.y || km[j * 8 + 5]) x[j * 8 + 5] = -INFINITY;
        if (v1.z || km[j * 8 + 6]) x[j * 8 + 6] = -INFINITY;
        if (v1.w || km[j * 8 + 7]) x[j * 8 + 7] = -INFINITY;
      }
    }
    float m = x[0];
#pragma unroll
    for (int i = 1; i < 16; ++i) m = fmaxf(m, x[i]);
#pragma unroll
    for (int o = 32; o > 0; o >>= 1) m = fmaxf(m, __shfl_xor(m, o));
    const float mc = m * C;
    float s = 0.f;
#pragma unroll
    for (int i = 0; i < 16; ++i) {
      x[i] = exp2f(__builtin_fmaf(x[i], C, -mc));
      s += x[i];
    }
#pragma unroll
    for (int o = 32; o > 0; o >>= 1) s += __shfl_xor(s, o);
    const float inv = 1.0f / s;
    unsigned short* prow = P + ((size_t)lhb << 20) + ((size_t)gq << 10);
#pragma unroll
    for (int j = 0; j < 2; ++j) {
      bhalf8 pv;
#pragma unroll
      for (int u = 0; u < 8; ++u) pv[u] = (short)f2bf(x[j * 8 + u] * inv);
      *(bhalf8*)(prow + j * 512 + lane * 8) = pv;
    }
  }
}

// ---------------------------------------------------------------------------
// outW[b][q][k] += (1/16) * sum_hh P[hh*4+b][q][k]   (this chunk's heads)
// ---------------------------------------------------------------------------
__global__ __launch_bounds__(256) void wmean_kernel(
    const unsigned short* __restrict__ P, float* __restrict__ outW,
    int nhh, int first) {
  const size_t gid = (size_t)blockIdx.x * 256 + threadIdx.x;  // one per 8 k
  const int k8 = (int)(gid & 127);
  const int q = (int)((gid >> 7) & 1023);
  const int b = (int)(gid >> 17);
  float s[8];
#pragma unroll
  for (int u = 0; u < 8; ++u) s[u] = 0.f;
  for (int hh = 0; hh < nhh; ++hh) {
    const int lhb = hh * 4 + b;
    bhalf8 v = *(const bhalf8*)(P + ((size_t)lhb << 20) + ((size_t)q << 10) + k8 * 8);
#pragma unroll
    for (int u = 0; u < 8; ++u) s[u] += bf2f((unsigned short)v[u]);
  }
  float* o = outW + (((size_t)(b * S_ + q)) << 10) + k8 * 8;
  const float invH = 1.0f / 16.0f;
  float4 v0, v1;
  v0.x = s[0] * invH; v0.y = s[1] * invH; v0.z = s[2] * invH; v0.w = s[3] * invH;
  v1.x = s[4] * invH; v1.y = s[5] * invH; v1.z = s[6] * invH; v1.w = s[7] * invH;
  if (!first) {
    float4 a = *(float4*)o, b4 = *(float4*)(o + 4);
    v0.x += a.x; v0.y += a.y; v0.z += a.z; v0.w += a.w;
    v1.x += b4.x; v1.y += b4.y; v1.z += b4.z; v1.w += b4.w;
  }
  *(float4*)o = v0;
  *(float4*)(o + 4) = v1;
}

// ---------------------------------------------------------------------------
// PV: Ocat[b][q][h*64+d] = sum_k P[lhb][q][k] * Vt[bh*64+d][k]
// 64q x 64d per block, BK=64, 4 waves in 2x2. grid (16 qtiles, CH)
// ---------------------------------------------------------------------------
__global__ __launch_bounds__(256) void pv_mfma_kernel(
    const unsigned short* __restrict__ Wt, const unsigned short* __restrict__ Vt,
    unsigned short* __restrict__ Ocat, int hb0) {
  const int lhb = blockIdx.y, hb = hb0 + lhb;
  const int h = hb >> 2, b = hb & 3;
  const int q0 = blockIdx.x * 64;
  __shared__ unsigned short Ps[64 * 64];
  __shared__ unsigned short Vs[64 * 64];
  const int t = threadIdx.x, wave = t >> 6, lane = t & 63;
  const int wr = wave >> 1, wc = wave & 1;
  const unsigned short* Wh = Wt + ((size_t)lhb << 20);
  const unsigned short* Vh = Vt + (size_t)(b * 16 + h) * 65536;
  floatx4 acc[2][2];
  const floatx4 z4 = {0.f, 0.f, 0.f, 0.f};
#pragma unroll
  for (int i = 0; i < 2; ++i)
#pragma unroll
    for (int j = 0; j < 2; ++j) acc[i][j] = z4;

  for (int k0 = 0; k0 < 1024; k0 += 64) {
    stage_tile<8>(Wh + (size_t)q0 * 1024 + k0, Ps, wave, lane);
    stage_tile<8>(Vh + k0, Vs, wave, lane);
    __syncthreads();
#pragma unroll
    for (int ks = 0; ks < 2; ++ks) {
      const int kb = ks * 64 + ((lane >> 4) << 4);
      bhalf8 af[2], bf[2];
#pragma unroll
      for (int mi = 0; mi < 2; ++mi)
        af[mi] = read_frag(Ps, wr * 32 + mi * 16 + (lane & 15), kb);
#pragma unroll
      for (int ni = 0; ni < 2; ++ni)
        bf[ni] = read_frag(Vs, wc * 32 + ni * 16 + (lane & 15), kb);
#pragma unroll
      for (int mi = 0; mi < 2; ++mi)
#pragma unroll
        for (int ni = 0; ni < 2; ++ni)
          acc[mi][ni] = __builtin_amdgcn_mfma_f32_16x16x32_bf16(af[mi], bf[ni], acc[mi][ni], 0, 0, 0);
    }
    __syncthreads();
  }
#pragma unroll
  for (int mi = 0; mi < 2; ++mi)
#pragma unroll
    for (int ni = 0; ni < 2; ++ni) {
      const int d = wc * 32 + ni * 16 + (lane & 15);
#pragma unroll
      for (int r = 0; r < 4; ++r) {
        const int q = q0 + wr * 32 + mi * 16 + (lane >> 4) * 4 + r;
        Ocat[((size_t)(b * S_) + q) * E_ + h * HD_ + d] = f2bf(acc[mi][ni][r]);
      }
    }
}

// ---------------------------------------------------------------------------
extern "C" void kernel_launch(void* const* d_in, const int* in_sizes, int n_in,
                              void* d_out, int out_size, void* d_ws, size_t ws_size,
                              hipStream_t stream) {
  (void)in_sizes; (void)n_in; (void)out_size;
  const float* query = (const float*)d_in[0];
  const float* key   = (const float*)d_in[1];
  const float* value = (const float*)d_in[2];
  const int* qidx = (const int*)d_in[3];
  const int* kidx = (const int*)d_in[4];
  const void* amask = d_in[5];
  const void* kpm   = d_in[6];
  const float* Wq = (const float*)d_in[7];
  const float* bq = (const float*)d_in[8];
  const float* Wk = (const float*)d_in[9];
  const float* bk = (const float*)d_in[10];
  const float* Wv = (const float*)d_in[11];
  const float* bv = (const float*)d_in[12];
  const float* Wo = (const float*)d_in[13];
  const float* bo = (const float*)d_in[14];

  float* outA = (float*)d_out;                          // [B,S,E] fp32
  float* outW = (float*)d_out + (size_t)B_ * S_ * E_;   // [B,S,S] fp32

  float* ws = (float*)d_ws;
  unsigned short* Ab   = (unsigned short*)(ws + 0);         // 3x 4,194,304 bf16
  unsigned short* Wb   = (unsigned short*)(ws + 6291456);   // 4x 1,048,576 bf16
  unsigned short* Qr   = (unsigned short*)(ws + 8388608);
  unsigned short* Kr   = (unsigned short*)(ws + 10485760);
  unsigned short* Vr   = (unsigned short*)(ws + 12582912);
  unsigned short* Vt   = (unsigned short*)(ws + 14680064);
  unsigned short* Ocat = (unsigned short*)(ws + 16777216);
  int* flagp           = (int*)(ws + 18874368);
  const size_t tail_off = 18874432;  // floats

  // P chunk: per head-batch 1024*1024 bf16 = 524288 floats.
  const size_t ws_floats = ws_size / 4;
  int CH = 0;
  unsigned short* P = nullptr;
  for (int c = 64; c >= 4; c >>= 1) {
    if (tail_off + (size_t)c * 524288 <= ws_floats) {
      CH = c;
      P = (unsigned short*)(ws + tail_off);
      break;
    }
  }
  if (!CH) {  // alias the Ab region (dead after the QKV GEMM): 6.29M floats >= 8 planes
    CH = 8;
    P = (unsigned short*)ws;
  }

  detect_bool_kernel<<<1, 64, 0, stream>>>((const uint8_t*)amask, flagp);

  cvt_in_kernel<<<dim3(2048, 1, 3), 256, 0, stream>>>(query, key, value, Ab);
  cvt_w_kernel<<<dim3(512, 1, 4), 256, 0, stream>>>(Wq, Wk, Wv, Wo, Wb);

  mfma_gemm_kernel<true><<<dim3(8, 32, 3), 256, 0, stream>>>(
      Ab, Ab + 4194304, Ab + 8388608,
      Wb, Wb + 1048576, Wb + 2097152,
      bq, bk, bv, Qr, Kr, Vr);

  rope_bf_kernel<<<8192, 256, 0, stream>>>((unsigned int*)Qr, qidx);
  rope_bf_kernel<<<8192, 256, 0, stream>>>((unsigned int*)Kr, kidx);

  transpose_v_kernel<<<dim3(16, 64), 256, 0, stream>>>(Vr, Vt);

  const int nch = HB_ / CH;
  for (int c = 0; c < nch; ++c) {
    const int hb0 = c * CH;
    fused_sm_kernel<<<dim3(64, CH), 256, 0, stream>>>(Qr, Kr, P, amask, kpm,
                                                      flagp, hb0);
    wmean_kernel<<<2048, 256, 0, stream>>>(P, outW, CH / 4, (c == 0) ? 1 : 0);
    pv_mfma_kernel<<<dim3(16, CH), 256, 0, stream>>>(P, Vt, Ocat, hb0);
  }

  mfma_gemm_kernel<false><<<dim3(8, 32, 1), 256, 0, stream>>>(
      Ocat, Ocat, Ocat, Wb + 3145728, Wb + 3145728, Wb + 3145728,
      bo, bo, bo, outA, outA, outA);
}